// Round 1
// baseline (500.893 us; speedup 1.0000x reference)
//
#include <hip/hip_runtime.h>
#include <cstddef>

#define NFRM 247
#define NBIN 128
#define NC   32
#define NWIN 58

// ---------------- K1: STFT (16x16 split DFT, bins 1..128) ----------------
// spec layout: (b, frame, f-1, c) float2
__global__ __launch_bounds__(128) void k_stft(const float* __restrict__ x,
                                              float2* __restrict__ spec) {
  const int gid = blockIdx.x;          // (b*32+c)*247 + fr
  const int fr  = gid % NFRM;
  const int bc  = gid / NFRM;
  const int tid = threadIdx.x;

  __shared__ float  xw[256];
  __shared__ float2 tw[256];
  __shared__ float2 Y[256];            // [f0][t0]

  const float* xp = x + ((size_t)bc * 16000 + (size_t)fr * 64);

  #pragma unroll
  for (int k = 0; k < 2; ++k) {
    const int t = tid + k * 128;
    const float wv = 0.5f - 0.5f * __cosf((float)t * 0.024639942f); // 2pi/255 (np.hanning)
    xw[t] = xp[t] * wv * 0.10226200f;                               // / ||w||  (||w||^2 = 95.625)
    float sv, cv;
    __sincosf((float)t * 0.024543693f, &sv, &cv);                   // 2pi/256
    tw[t] = make_float2(cv, -sv);                                   // e^{-2pi i m/256}
  }
  __syncthreads();

  // stage A: Y[f0][t0] = sum_t1 xw[16*t1+t0] * e^{-2pi i f0 t1/16}
  #pragma unroll
  for (int k = 0; k < 2; ++k) {
    const int e = tid + k * 128;
    const int f0 = e >> 4, t0 = e & 15;
    const int step = (f0 << 4) & 255;
    float re = 0.f, im = 0.f;
    int m = 0;
    #pragma unroll
    for (int t1 = 0; t1 < 16; ++t1) {
      const float v = xw[(t1 << 4) + t0];
      const float2 w = tw[m];
      re = fmaf(v, w.x, re);
      im = fmaf(v, w.y, im);
      m = (m + step) & 255;
    }
    Y[e] = make_float2(re, im);
  }
  __syncthreads();

  // stage B: spec[f] = sum_t0 Y[f&15][t0] * e^{-2pi i f t0/256},  f = tid+1
  const int f = tid + 1;               // 1..128
  const int f0 = f & 15;
  float re = 0.f, im = 0.f;
  int m = 0;
  #pragma unroll
  for (int t0 = 0; t0 < 16; ++t0) {
    const float2 yv = Y[(f0 << 4) + t0];
    const float2 w = tw[m];
    re += yv.x * w.x - yv.y * w.y;
    im += yv.x * w.y + yv.y * w.x;
    m = (m + f) & 255;
  }
  const int b = bc >> 5, c = bc & 31;
  spec[(((size_t)b * NFRM + fr) * NBIN + (f - 1)) * NC + c] = make_float2(re, im);
}

// ---------------- K2: CSD + |.|^2 + band average ----------------
// banded layout: (b*58+t, k, i, j) float
__global__ __launch_bounds__(256) void k_csd(const float2* __restrict__ spec,
                                             float* __restrict__ banded) {
  const int bt  = blockIdx.x;          // b*58 + t
  const int b   = bt / NWIN, t = bt % NWIN;
  const int tid = threadIdx.x;
  const int wv  = tid >> 6;            // wave 0..3
  const int lane = tid & 63;
  const int i0 = (lane >> 3) * 4;
  const int j0 = (lane & 7) * 4;

  __shared__ float red[6 * 1024];                   // 24KB; first 16KB doubles as staging
  float2* Xs = (float2*)(red + wv * 1024);          // per-wave [16][32] float2

  float bacc[6][16];
  #pragma unroll
  for (int k = 0; k < 6; ++k)
    #pragma unroll
    for (int e = 0; e < 16; ++e) bacc[k][e] = 0.f;

  const float2* sb = spec + (size_t)b * NFRM * NBIN * NC;

  for (int it = 0; it < 32; ++it) {
    const int f = 1 + wv + it * 4;     // wave-uniform bin
    // stage X[s][c] = spec[b][t*4+s][f-1][c]
    #pragma unroll
    for (int r = 0; r < 8; ++r) {
      const int e = lane + r * 64;
      const int s = e >> 5, cc = e & 31;
      Xs[e] = sb[((size_t)(t * 4 + s) * NBIN + (f - 1)) * NC + cc];
    }
    __syncthreads();

    float accRe[16], accIm[16];
    #pragma unroll
    for (int e = 0; e < 16; ++e) { accRe[e] = 0.f; accIm[e] = 0.f; }

    #pragma unroll
    for (int s = 0; s < 16; ++s) {
      float2 xi[4], xj[4];
      #pragma unroll
      for (int a = 0; a < 4; ++a) {
        xi[a] = Xs[s * 32 + i0 + a];
        xj[a] = Xs[s * 32 + j0 + a];
      }
      #pragma unroll
      for (int a = 0; a < 4; ++a)
        #pragma unroll
        for (int d = 0; d < 4; ++d) {
          const int e = a * 4 + d;
          // M_ij += x_i * conj(x_j)
          accRe[e] = fmaf(xi[a].x, xj[d].x, fmaf(xi[a].y, xj[d].y, accRe[e]));
          accIm[e] = fmaf(xi[a].y, xj[d].x, fmaf(-xi[a].x, xj[d].y, accIm[e]));
        }
    }

    #define ACCB(K) { _Pragma("unroll") \
      for (int e = 0; e < 16; ++e) { float rr = accRe[e], ii = accIm[e]; \
        bacc[K][e] = fmaf(rr, rr, fmaf(ii, ii, bacc[K][e])); } }
    if      (f <= 3)  ACCB(0)
    else if (f <= 6)  ACCB(1)
    else if (f <= 12) ACCB(2)
    else if (f <= 25) ACCB(3)
    else if (f <= 51) ACCB(4)
    else              ACCB(5)
    #undef ACCB
    __syncthreads();
  }

  // cross-wave reduction in LDS
  for (int w2 = 0; w2 < 4; ++w2) {
    if (wv == w2) {
      #pragma unroll
      for (int k = 0; k < 6; ++k)
        #pragma unroll
        for (int a = 0; a < 4; ++a)
          #pragma unroll
          for (int d = 0; d < 4; ++d) {
            const int idx = k * 1024 + (i0 + a) * 32 + (j0 + d);
            const float v = bacc[k][a * 4 + d];
            if (w2 == 0) red[idx] = v; else red[idx] += v;
          }
    }
    __syncthreads();
  }

  // scale: |M/16|^2 / band_count  = raw/(256*cnt),  cnt = {3,3,6,13,26,77}
  float* op = banded + (size_t)bt * 6144;
  for (int u = tid; u < 6144; u += 256) {
    const int k = u >> 10;
    float scl;
    if      (k <= 1) scl = 1.f / 768.f;
    else if (k == 2) scl = 1.f / 1536.f;
    else if (k == 3) scl = 1.f / 3328.f;
    else if (k == 4) scl = 1.f / 6656.f;
    else             scl = 1.f / 19712.f;
    op[u] = red[u] * scl;
  }
}

// ---------------- K3: one-sided Jacobi eig + matrix log ----------------
// 2 matrices per 64-thread block: lanes 0-31 -> matrix 2*blk, 32-63 -> 2*blk+1.
// Each lane owns one column of G (G starts = A; at convergence g_c = lambda_c v_c).
__global__ __launch_bounds__(64) void k_eig(const float* __restrict__ banded,
                                            float* __restrict__ out) {
  const int blk  = blockIdx.x;
  const int lane = threadIdx.x;
  const int h    = lane >> 5;
  const int c    = lane & 31;

  __shared__ float sW[2][32][33];
  __shared__ float sS[2][32];

  {
    const float* src = banded + (size_t)blk * 2048;
    for (int u = lane; u < 2048; u += 64)
      sW[u >> 10][(u & 1023) >> 5][u & 31] = src[u];
  }
  __syncthreads();

  float g[32];
  #pragma unroll
  for (int i = 0; i < 32; ++i) g[i] = sW[h][i][c];

  float n = 0.f;
  #pragma unroll
  for (int i = 0; i < 32; ++i) n = fmaf(g[i], g[i], n);

  const float EPS2 = 1e-12f;          // skip rotation when bpq^2 <= EPS2*n*np
  #pragma unroll 1
  for (int sweep = 0; sweep < 12; ++sweep) {
    int anybad = 0;
    #pragma unroll 1
    for (int m = 1; m < 32; ++m) {    // XOR-mask pairing: partner column = c^m
      const int pidx = (lane ^ m) << 2;
      float tmp[32];
      #pragma unroll
      for (int e = 0; e < 32; ++e)
        tmp[e] = __int_as_float(__builtin_amdgcn_ds_bpermute(pidx, __float_as_int(g[e])));
      const float np = __int_as_float(__builtin_amdgcn_ds_bpermute(pidx, __float_as_int(n)));

      float d0 = 0.f, d1 = 0.f, d2 = 0.f, d3 = 0.f;
      #pragma unroll
      for (int e = 0; e < 32; e += 4) {
        d0 = fmaf(g[e + 0], tmp[e + 0], d0);
        d1 = fmaf(g[e + 1], tmp[e + 1], d1);
        d2 = fmaf(g[e + 2], tmp[e + 2], d2);
        d3 = fmaf(g[e + 3], tmp[e + 3], d3);
      }
      const float bpq = (d0 + d1) + (d2 + d3);   // bitwise-identical on both pair lanes

      const int bad = (bpq * bpq > EPS2 * n * np);
      anybad |= bad;
      if (bad) {
        // own-perspective: tau_f = (np-n)/(2 bpq); update g' = c*(g - t_f*partner)
        const float tau = (np - n) * 0.5f / bpq;
        float tf = 1.f / (fabsf(tau) + sqrtf(fmaf(tau, tau, 1.f)));
        if (tau < 0.f) tf = -tf;
        const float cr = rsqrtf(fmaf(tf, tf, 1.f));
        const float sg = -tf * cr;
        n = fmaf(-tf, bpq, n);
        #pragma unroll
        for (int e = 0; e < 32; ++e) g[e] = fmaf(sg, tmp[e], cr * g[e]);
      }
    }
    if (!__any(anybad)) break;
  }

  // exact norm; lambda = sqrt(nx); log with eigval floor 100*eps folded: 0.5*log(max(nx, floor^2))
  float n0 = 0.f, n1 = 0.f, n2 = 0.f, n3 = 0.f;
  #pragma unroll
  for (int e = 0; e < 32; e += 4) {
    n0 = fmaf(g[e + 0], g[e + 0], n0);
    n1 = fmaf(g[e + 1], g[e + 1], n1);
    n2 = fmaf(g[e + 2], g[e + 2], n2);
    n3 = fmaf(g[e + 3], g[e + 3], n3);
  }
  const float nx = (n0 + n1) + (n2 + n3);
  const float lv = 0.5f * logf(fmaxf(nx, 1.4210855e-10f));
  const float sc = (nx > 1e-32f) ? (lv / nx) : 0.f;   // out = sum_c (lv/||g||^2) g g^T

  __syncthreads();
  #pragma unroll
  for (int i = 0; i < 32; ++i) sW[h][i][c] = g[i];
  sS[h][c] = sc;
  __syncthreads();

  float u[32];
  #pragma unroll
  for (int e = 0; e < 32; ++e) u[e] = sW[h][c][e] * sS[h][e];

  const int mat = blk * 2 + h;         // (b*58+t)*6 + k
  const int kq = mat % 6, bq = mat / 6;
  const int bb = bq / NWIN, tt = bq % NWIN;
  // out[b][k][i=c][j][t]
  float* obase = out + ((size_t)((bb * 6 + kq) * 32 + c) * 32) * NWIN + tt;

  #pragma unroll 4
  for (int j = 0; j < 32; ++j) {
    float a0 = 0.f, a1 = 0.f, a2 = 0.f, a3 = 0.f;
    #pragma unroll
    for (int e = 0; e < 32; e += 4) {
      a0 = fmaf(u[e + 0], sW[h][j][e + 0], a0);
      a1 = fmaf(u[e + 1], sW[h][j][e + 1], a1);
      a2 = fmaf(u[e + 2], sW[h][j][e + 2], a2);
      a3 = fmaf(u[e + 3], sW[h][j][e + 3], a3);
    }
    obase[(size_t)j * NWIN] = (a0 + a1) + (a2 + a3);
  }
}

extern "C" void kernel_launch(void* const* d_in, const int* in_sizes, int n_in,
                              void* d_out, int out_size, void* d_ws, size_t ws_size,
                              hipStream_t stream) {
  const float* x = (const float*)d_in[0];
  float* outp = (float*)d_out;

  float2* spec  = (float2*)d_ws;                                  // 8*247*128*32 float2 = 64.75 MB
  float* banded = (float*)((char*)d_ws + (size_t)8 * NFRM * NBIN * NC * sizeof(float2)); // 11.4 MB

  k_stft<<<dim3(8 * 32 * NFRM), dim3(128), 0, stream>>>(x, spec);
  k_csd <<<dim3(8 * NWIN),      dim3(256), 0, stream>>>(spec, banded);
  k_eig <<<dim3(8 * NWIN * 6 / 2), dim3(64), 0, stream>>>(banded, outp);
}